// Round 11
// baseline (248.466 us; speedup 1.0000x reference)
//
#include <hip/hip_runtime.h>
#include <hip/hip_bf16.h>
#include <stdint.h>

#define NNODES 50000
#define NEDGES 800000
#define FDIM   128
#define NCLS   4
#define NB     196        // buckets of 256 nodes
#define ECAP   6144      // LDS edge-stage capacity per bucket (mean 4082)
#define LPITCH 136        // LDS row pitch in u16 (272B)
#define NPH    8          // source phases (src>>13) for gather L2 locality
#define SCAP   768        // LDS csr-slice capacity in k_agg (16 nodes, mean 256)
#define SCAP2  1536       // LDS csr-slice capacity in k_aggmfma (64 nodes, mean 1024)

typedef uint32_t u32;
typedef unsigned char u8;
typedef unsigned short u16;
typedef __bf16 bf16x8 __attribute__((ext_vector_type(8)));
typedef float f32x4 __attribute__((ext_vector_type(4)));
typedef float f32x2 __attribute__((ext_vector_type(2)));

__device__ __forceinline__ u16 f2bf(float f) {
    u32 u = __float_as_uint(f);
    u32 r = u + 0x7fffu + ((u >> 16) & 1u);
    return (u16)(r >> 16);
}
__device__ __forceinline__ u32 pack2(float a, float b) {
    return (u32)f2bf(a) | ((u32)f2bf(b) << 16);
}
__device__ __forceinline__ float bflo(u32 p) { return __uint_as_float(p << 16); }
__device__ __forceinline__ float bfhi(u32 p) { return __uint_as_float(p & 0xffff0000u); }

// 8 bf16 (as uint4 halves) -> 8 fp8 e4m3 packed in uint2 (hardware RNE)
__device__ __forceinline__ uint2 bf8x8_from_bf16(uint4 v) {
    uint2 o;
    o.x = __builtin_amdgcn_cvt_pk_fp8_f32(bflo(v.x), bfhi(v.x), 0,   false);
    o.x = __builtin_amdgcn_cvt_pk_fp8_f32(bflo(v.y), bfhi(v.y), o.x, true);
    o.y = __builtin_amdgcn_cvt_pk_fp8_f32(bflo(v.z), bfhi(v.z), 0,   false);
    o.y = __builtin_amdgcn_cvt_pk_fp8_f32(bflo(v.w), bfhi(v.w), o.y, true);
    return o;
}
// accumulate 8 fp8 lanes into a0..a7
__device__ __forceinline__ void acc8(uint2 v, float& a0, float& a1, float& a2,
                                     float& a3, float& a4, float& a5, float& a6,
                                     float& a7) {
    f32x2 p0 = __builtin_amdgcn_cvt_pk_f32_fp8(v.x, false);
    f32x2 p1 = __builtin_amdgcn_cvt_pk_f32_fp8(v.x, true);
    f32x2 p2 = __builtin_amdgcn_cvt_pk_f32_fp8(v.y, false);
    f32x2 p3 = __builtin_amdgcn_cvt_pk_f32_fp8(v.y, true);
    a0 += p0.x; a1 += p0.y; a2 += p1.x; a3 += p1.y;
    a4 += p2.x; a5 += p2.y; a6 += p3.x; a7 += p3.y;
}

// ================= K1: bucket histogram + both weight packs =================
__global__ void __launch_bounds__(256) k_pre(
        const int* __restrict__ dst,
        const float* __restrict__ Wl0, const float* __restrict__ Wr0,
        const float* __restrict__ Wl1, const float* __restrict__ Wr1,
        int* __restrict__ bcnt, u16* __restrict__ Bp0, u16* __restrict__ Bp1) {
    int t = threadIdx.x;
    int bid = blockIdx.x;
    if (bid < 782) {                 // ---- bhist ----
        __shared__ int h[NB];
        if (t < NB) h[t] = 0;
        __syncthreads();
        int base = bid * 1024;
#pragma unroll
        for (int i = 0; i < 4; ++i) {
            int e = base + i * 256 + t;
            if (e < NEDGES) atomicAdd(&h[dst[e] >> 8], 1);
        }
        __syncthreads();
        if (t < NB) {
            int v = h[t];
            if (v) atomicAdd(&bcnt[t], v);
        }
    } else {                          // ---- weight pack (128 blocks per layer) ----
        int layer = (bid < 910) ? 0 : 1;
        int pid = bid - (layer ? 910 : 782);
        int tid = pid * 256 + t;      // 0..32767
        int j    = tid & 7;
        int lane = (tid >> 3) & 63;
        int ks   = (tid >> 9) & 3;
        int nt   = tid >> 11;
        int col  = nt * 16 + (lane & 15);
        int k    = ks * 32 + (lane >> 4) * 8 + j;
        const float* Wl = layer ? Wl1 : Wl0;
        const float* Wr = layer ? Wr1 : Wr0;
        float v = (col < FDIM) ? Wl[k * FDIM + col] : Wr[k * FDIM + (col - FDIM)];
        (layer ? Bp1 : Bp0)[tid] = f2bf(v);
    }
}

// ============ K2: layer-0 MFMA (blocks 0..781) + edge scatter (782..1563) ===
// y0 written as fp8 e4m3; zb bf16. ebuf must NOT alias y0/zb.
__global__ void __launch_bounds__(256) k_scatmfma(
        const float* __restrict__ x, const uint4* __restrict__ Bp,
        const float* __restrict__ bias, u8* __restrict__ y, u16* __restrict__ zb,
        const int* __restrict__ src, const int* __restrict__ dst,
        const int* __restrict__ bcnt, int* __restrict__ bcur,
        u32* __restrict__ ebuf) {
    __shared__ u16 sA[64 * LPITCH];   // 17408 B; scatter half aliases ints onto it
    int t = threadIdx.x;
    if (blockIdx.x < 782) {
        int blk = blockIdx.x;
        int wave = t >> 6, lane = t & 63, m = lane & 15, quad = lane >> 4;
        {
            int row = t >> 2, q = t & 3;
            int r = blk * 64 + row;
            if (r >= NNODES) r = NNODES - 1;
            const float4* gs = (const float4*)(x + (size_t)r * FDIM) + q * 8;
            uint4* ld = (uint4*)(sA + row * LPITCH + q * 32);
#pragma unroll
            for (int i = 0; i < 4; ++i) {
                float4 a = gs[2 * i], b = gs[2 * i + 1];
                uint4 v;
                v.x = pack2(a.x, a.y); v.y = pack2(a.z, a.w);
                v.z = pack2(b.x, b.y); v.w = pack2(b.z, b.w);
                ld[i] = v;
            }
        }
        uint4 breg[4][4];
#pragma unroll
        for (int ks = 0; ks < 4; ++ks)
#pragma unroll
            for (int nt = 0; nt < 4; ++nt)
                breg[ks][nt] = Bp[((wave * 4 + nt) * 4 + ks) * 64 + lane];
        __syncthreads();
        bf16x8 a[4][4];
#pragma unroll
        for (int mt = 0; mt < 4; ++mt)
#pragma unroll
            for (int ks = 0; ks < 4; ++ks)
                a[mt][ks] = __builtin_bit_cast(bf16x8,
                    *(const uint4*)(sA + (mt * 16 + m) * LPITCH + ks * 32 + quad * 8));
        f32x4 acc[4][4];
#pragma unroll
        for (int mt = 0; mt < 4; ++mt)
#pragma unroll
            for (int nt = 0; nt < 4; ++nt) acc[mt][nt] = (f32x4){0.f, 0.f, 0.f, 0.f};
#pragma unroll
        for (int ks = 0; ks < 4; ++ks)
#pragma unroll
            for (int nt = 0; nt < 4; ++nt) {
                bf16x8 b = __builtin_bit_cast(bf16x8, breg[ks][nt]);
#pragma unroll
                for (int mt = 0; mt < 4; ++mt)
                    acc[mt][nt] = __builtin_amdgcn_mfma_f32_16x16x32_bf16(
                        a[mt][ks], b, acc[mt][nt], 0, 0, 0);
            }
        __syncthreads();
        if (wave < 2) {
#pragma unroll
            for (int nt = 0; nt < 4; ++nt) {
                int col = (wave * 4 + nt) * 16 + m;
#pragma unroll
                for (int mt = 0; mt < 4; ++mt)
#pragma unroll
                    for (int r = 0; r < 4; ++r)
                        sA[(mt * 16 + quad * 4 + r) * LPITCH + col] = f2bf(acc[mt][nt][r]);
            }
        }
        __syncthreads();
#pragma unroll
        for (int i = 0; i < 4; ++i) {
            int g = i * 256 + t, row = g >> 4, ch = g & 15;
            int gr = blk * 64 + row;
            if (gr < NNODES) {
                uint4 v = *(const uint4*)(sA + row * LPITCH + ch * 8);
                *((uint2*)(y + (size_t)gr * FDIM) + ch) = bf8x8_from_bf16(v);
            }
        }
        __syncthreads();
        if (wave >= 2) {
#pragma unroll
            for (int nt = 0; nt < 4; ++nt) {
                int col = (wave * 4 + nt) * 16 + m - 128;
                float bv = bias[col];
#pragma unroll
                for (int mt = 0; mt < 4; ++mt)
#pragma unroll
                    for (int r = 0; r < 4; ++r)
                        sA[(mt * 16 + quad * 4 + r) * LPITCH + col] = f2bf(acc[mt][nt][r] + bv);
            }
        }
        __syncthreads();
#pragma unroll
        for (int i = 0; i < 4; ++i) {
            int g = i * 256 + t, row = g >> 4, ch = g & 15;
            int gr = blk * 64 + row;
            if (gr < NNODES)
                *((uint4*)(zb + (size_t)gr * FDIM) + ch) =
                    *(const uint4*)(sA + row * LPITCH + ch * 8);
        }
    } else {
        // ---------------- edge bucket scatter (with in-LDS bucket scan) -------
        int* hh = (int*)sA;
        int* bb = hh + 256;
        int* ss = bb + 256;
        int v = (t < NB) ? bcnt[t] : 0;
        ss[t] = v;
        __syncthreads();
        for (int off = 1; off < 256; off <<= 1) {
            int u = (t >= off) ? ss[t - off] : 0;
            __syncthreads();
            ss[t] += u;
            __syncthreads();
        }
        int boff = ss[t] - v;
        hh[t] = 0;
        __syncthreads();
        int eb = (blockIdx.x - 782) * 1024;
        int mb[4];
        u32 pk[4];
#pragma unroll
        for (int i = 0; i < 4; ++i) {
            int e = eb + i * 256 + t;
            if (e < NEDGES) {
                int d = dst[e];
                mb[i] = d >> 8;
                pk[i] = (u32)src[e] | ((u32)d << 16);
                atomicAdd(&hh[mb[i]], 1);
            } else mb[i] = -1;
        }
        __syncthreads();
        if (t < NB) {
            int c = hh[t];
            bb[t] = c ? (boff + atomicAdd(&bcur[t], c)) : 0;
            hh[t] = 0;
        }
        __syncthreads();
#pragma unroll
        for (int i = 0; i < 4; ++i) {
            if (mb[i] >= 0) {
                int r = atomicAdd(&hh[mb[i]], 1);
                ebuf[bb[mb[i]] + r] = pk[i];
            }
        }
    }
}

// ======= K3: per-bucket CSR finalize, phase-sorted (self-scans bcnt) ========
__global__ void __launch_bounds__(256) k_bfinal(
        const u32* __restrict__ ebuf, const int* __restrict__ bcnt,
        int* __restrict__ offs, float* __restrict__ invd, int* __restrict__ csr) {
    __shared__ u32 se[ECAP];
    __shared__ int deg8[256 * NPH];
    __shared__ int s[256];
    int b = blockIdx.x, t = threadIdx.x;
    int nbase = b << 8;
    int v = (t < NB) ? bcnt[t] : 0;
    s[t] = v;
    __syncthreads();
    for (int off = 1; off < 256; off <<= 1) {
        int u = (t >= off) ? s[t - off] : 0;
        __syncthreads();
        s[t] += u;
        __syncthreads();
    }
    int ebeg = s[b] - bcnt[b];
    int ecnt = bcnt[b];
    __syncthreads();
#pragma unroll
    for (int j = 0; j < NPH; ++j) deg8[t * NPH + j] = 0;
    __syncthreads();
    for (int i = t; i < ecnt; i += 256) {
        u32 e = ebuf[ebeg + i];
        if (i < ECAP) se[i] = e;
        atomicAdd(&deg8[((int)(e >> 16) - nbase) * NPH + (((int)(e & 0xffffu)) >> 13)], 1);
    }
    __syncthreads();
    int pre[NPH];
    int run = 0;
#pragma unroll
    for (int j = 0; j < NPH; ++j) { pre[j] = run; run += deg8[t * NPH + j]; }
    int d = run;
    s[t] = d;
    __syncthreads();
    for (int off = 1; off < 256; off <<= 1) {
        int u = (t >= off) ? s[t - off] : 0;
        __syncthreads();
        s[t] += u;
        __syncthreads();
    }
    int ex = s[t] - d;
    int node = nbase + t;
    if (node < NNODES) {
        offs[node] = ebeg + ex;
        invd[node] = (d > 0) ? (1.0f / (float)d) : 0.0f;
    }
    __syncthreads();
#pragma unroll
    for (int j = 0; j < NPH; ++j) deg8[t * NPH + j] = ex + pre[j];
    __syncthreads();
    for (int i = t; i < ecnt; i += 256) {
        u32 e = (i < ECAP) ? se[i] : ebuf[ebeg + i];
        int dl = (int)(e >> 16) - nbase;
        int sv = (int)(e & 0xffffu);
        int r = atomicAdd(&deg8[dl * NPH + (sv >> 13)], 1);
        csr[ebeg + r] = sv;
    }
    if (b == 0 && t == 0) offs[NNODES] = NEDGES;
}

// ===== K45: fused layer-0 aggregation + layer-1 MFMA ========================
// Block owns 64 node rows. Phase A: gather y0 (fp8), h = relu(iv*agg + zb)
// written as bf16 straight into the LDS A-tile. Phase B: dual GEMM with
// streamed a/b fragments (low VGPR peak), y1 fp8 + zb bf16 out.
// zb: reads own rows then overwrites own rows — no cross-block hazard.
__global__ void __launch_bounds__(256) k_aggmfma(
        const u8* __restrict__ y0, const int* __restrict__ offs,
        const int* __restrict__ csr, const float* __restrict__ invd,
        const uint4* __restrict__ Bp, const float* __restrict__ bias,
        u8* __restrict__ y1, u16* __restrict__ zb) {
    __shared__ u16 sA[64 * LPITCH];
    __shared__ int sidx[SCAP2];
    int t = threadIdx.x;
    int blk = blockIdx.x;
    int n0 = blk * 64;
    int nend = (n0 + 64 < NNODES) ? (n0 + 64) : NNODES;
    int base0 = offs[n0];
    int ecnt = offs[nend] - base0;
    for (int i = t; i < ecnt && i < SCAP2; i += 256) sidx[i] = csr[base0 + i];
    __syncthreads();
    int g = t >> 4, q = t & 15;
    const u8* yq = y0 + q * 8;
#pragma unroll
    for (int j = 0; j < 4; ++j) {
        int lr = g * 4 + j;
        int n = n0 + lr;
        uint4 hout = make_uint4(0, 0, 0, 0);
        if (n < NNODES) {
            int beg = offs[n], end = offs[n + 1];
            float a0 = 0, a1 = 0, a2 = 0, a3 = 0, a4 = 0, a5 = 0, a6 = 0, a7 = 0;
            int ii = beg;
            for (; ii + 8 <= end; ii += 8) {
                int li = ii - base0;
                int s[8];
                if (li + 7 < SCAP2) {
#pragma unroll
                    for (int k = 0; k < 8; ++k) s[k] = sidx[li + k];
                } else {
#pragma unroll
                    for (int k = 0; k < 8; ++k) s[k] = csr[ii + k];
                }
                uint2 v[8];
#pragma unroll
                for (int k = 0; k < 8; ++k)
                    v[k] = *(const uint2*)(yq + (size_t)s[k] * FDIM);
#pragma unroll
                for (int k = 0; k < 8; ++k)
                    acc8(v[k], a0, a1, a2, a3, a4, a5, a6, a7);
            }
            for (; ii < end; ++ii) {
                int li = ii - base0;
                int s = (li < SCAP2) ? sidx[li] : csr[ii];
                uint2 v = *(const uint2*)(yq + (size_t)s * FDIM);
                acc8(v, a0, a1, a2, a3, a4, a5, a6, a7);
            }
            float iv = invd[n];
            uint4 zv = *(const uint4*)(zb + (size_t)n * FDIM + q * 8);
            float r0 = fmaxf(fmaf(a0, iv, bflo(zv.x)), 0.f);
            float r1 = fmaxf(fmaf(a1, iv, bfhi(zv.x)), 0.f);
            float r2 = fmaxf(fmaf(a2, iv, bflo(zv.y)), 0.f);
            float r3 = fmaxf(fmaf(a3, iv, bfhi(zv.y)), 0.f);
            float r4 = fmaxf(fmaf(a4, iv, bflo(zv.z)), 0.f);
            float r5 = fmaxf(fmaf(a5, iv, bfhi(zv.z)), 0.f);
            float r6 = fmaxf(fmaf(a6, iv, bflo(zv.w)), 0.f);
            float r7 = fmaxf(fmaf(a7, iv, bfhi(zv.w)), 0.f);
            hout.x = pack2(r0, r1); hout.y = pack2(r2, r3);
            hout.z = pack2(r4, r5); hout.w = pack2(r6, r7);
        }
        *(uint4*)(sA + lr * LPITCH + q * 8) = hout;
    }
    __syncthreads();

    // ---- Phase B: dual GEMM, streamed fragments ----
    int wave = t >> 6, lane = t & 63, m = lane & 15, quad = lane >> 4;
    f32x4 acc[4][4];
#pragma unroll
    for (int mt = 0; mt < 4; ++mt)
#pragma unroll
        for (int nt = 0; nt < 4; ++nt) acc[mt][nt] = (f32x4){0.f, 0.f, 0.f, 0.f};
#pragma unroll
    for (int ks = 0; ks < 4; ++ks) {
        uint4 breg[4];
#pragma unroll
        for (int nt = 0; nt < 4; ++nt)
            breg[nt] = Bp[((wave * 4 + nt) * 4 + ks) * 64 + lane];
        bf16x8 a[4];
#pragma unroll
        for (int mt = 0; mt < 4; ++mt)
            a[mt] = __builtin_bit_cast(bf16x8,
                *(const uint4*)(sA + (mt * 16 + m) * LPITCH + ks * 32 + quad * 8));
#pragma unroll
        for (int nt = 0; nt < 4; ++nt) {
            bf16x8 b = __builtin_bit_cast(bf16x8, breg[nt]);
#pragma unroll
            for (int mt = 0; mt < 4; ++mt)
                acc[mt][nt] = __builtin_amdgcn_mfma_f32_16x16x32_bf16(
                    a[mt], b, acc[mt][nt], 0, 0, 0);
        }
    }
    __syncthreads();
    if (wave < 2) {
#pragma unroll
        for (int nt = 0; nt < 4; ++nt) {
            int col = (wave * 4 + nt) * 16 + m;
#pragma unroll
            for (int mt = 0; mt < 4; ++mt)
#pragma unroll
                for (int r = 0; r < 4; ++r)
                    sA[(mt * 16 + quad * 4 + r) * LPITCH + col] = f2bf(acc[mt][nt][r]);
        }
    }
    __syncthreads();
#pragma unroll
    for (int i = 0; i < 4; ++i) {
        int gg = i * 256 + t, row = gg >> 4, ch = gg & 15;
        int gr = n0 + row;
        if (gr < NNODES) {
            uint4 v = *(const uint4*)(sA + row * LPITCH + ch * 8);
            *((uint2*)(y1 + (size_t)gr * FDIM) + ch) = bf8x8_from_bf16(v);
        }
    }
    __syncthreads();
    if (wave >= 2) {
#pragma unroll
        for (int nt = 0; nt < 4; ++nt) {
            int col = (wave * 4 + nt) * 16 + m - 128;
            float bv = bias[col];
#pragma unroll
            for (int mt = 0; mt < 4; ++mt)
#pragma unroll
                for (int r = 0; r < 4; ++r)
                    sA[(mt * 16 + quad * 4 + r) * LPITCH + col] = f2bf(acc[mt][nt][r] + bv);
        }
    }
    __syncthreads();
#pragma unroll
    for (int i = 0; i < 4; ++i) {
        int gg = i * 256 + t, row = gg >> 4, ch = gg & 15;
        int gr = n0 + row;
        if (gr < NNODES)
            *((uint4*)(zb + (size_t)gr * FDIM) + ch) =
                *(const uint4*)(sA + row * LPITCH + ch * 8);
    }
}

// ===== K6: layer-1 aggregation + fused final-layer transform (unroll 8) =====
template <int RELU, int OUTBF, int FUSE4>
__global__ void __launch_bounds__(256) k_agg(
        const u8* __restrict__ y, const int* __restrict__ offs,
        const int* __restrict__ csr, const float* __restrict__ invd,
        const u16* __restrict__ zb, u16* __restrict__ outb, float* __restrict__ outf,
        const float* __restrict__ Wl2, const float* __restrict__ Wr2,
        const float* __restrict__ bl2, float* __restrict__ y4,
        float* __restrict__ outz) {
    __shared__ int sidx[SCAP];
    int t = threadIdx.x;
    int n0 = blockIdx.x * 16;
    int base0 = offs[n0];
    int ecnt = offs[n0 + 16] - base0;
    for (int i = t; i < ecnt && i < SCAP; i += 256) sidx[i] = csr[base0 + i];
    __syncthreads();
    int nl = t >> 4, q = t & 15;
    int n = n0 + nl;
    int beg = offs[n], end = offs[n + 1];
    float a0 = 0, a1 = 0, a2 = 0, a3 = 0, a4 = 0, a5 = 0, a6 = 0, a7 = 0;
    const u8* yq = y + q * 8;
    int ii = beg;
    for (; ii + 8 <= end; ii += 8) {
        int li = ii - base0;
        int s[8];
        if (li + 7 < SCAP) {
#pragma unroll
            for (int k = 0; k < 8; ++k) s[k] = sidx[li + k];
        } else {
#pragma unroll
            for (int k = 0; k < 8; ++k) s[k] = csr[ii + k];
        }
        uint2 v[8];
#pragma unroll
        for (int k = 0; k < 8; ++k)
            v[k] = *(const uint2*)(yq + (size_t)s[k] * FDIM);
#pragma unroll
        for (int k = 0; k < 8; ++k)
            acc8(v[k], a0, a1, a2, a3, a4, a5, a6, a7);
    }
    for (; ii < end; ++ii) {
        int li = ii - base0;
        int s = (li < SCAP) ? sidx[li] : csr[ii];
        uint2 v = *(const uint2*)(yq + (size_t)s * FDIM);
        acc8(v, a0, a1, a2, a3, a4, a5, a6, a7);
    }
    float iv = invd[n];
    uint4 zv = *(const uint4*)(zb + (size_t)n * FDIM + q * 8);
    float r0 = fmaf(a0, iv, bflo(zv.x)), r1 = fmaf(a1, iv, bfhi(zv.x));
    float r2 = fmaf(a2, iv, bflo(zv.y)), r3 = fmaf(a3, iv, bfhi(zv.y));
    float r4 = fmaf(a4, iv, bflo(zv.z)), r5 = fmaf(a5, iv, bfhi(zv.z));
    float r6 = fmaf(a6, iv, bflo(zv.w)), r7 = fmaf(a7, iv, bfhi(zv.w));
    if (RELU) {
        r0 = fmaxf(r0, 0.f); r1 = fmaxf(r1, 0.f); r2 = fmaxf(r2, 0.f); r3 = fmaxf(r3, 0.f);
        r4 = fmaxf(r4, 0.f); r5 = fmaxf(r5, 0.f); r6 = fmaxf(r6, 0.f); r7 = fmaxf(r7, 0.f);
    }
    if (OUTBF) {
        uint4 o;
        o.x = pack2(r0, r1); o.y = pack2(r2, r3);
        o.z = pack2(r4, r5); o.w = pack2(r6, r7);
        *(uint4*)(outb + (size_t)n * FDIM + q * 8) = o;
    } else {
        float* o = outf + (size_t)n * FDIM + q * 8;
        ((float4*)o)[0] = make_float4(r0, r1, r2, r3);
        ((float4*)o)[1] = make_float4(r4, r5, r6, r7);
    }
    if (FUSE4) {
        float rr[8] = {r0, r1, r2, r3, r4, r5, r6, r7};
        float4 py = {0, 0, 0, 0}, pz = {0, 0, 0, 0};
        const float4* wl4 = (const float4*)Wl2;
        const float4* wr4 = (const float4*)Wr2;
#pragma unroll
        for (int j = 0; j < 8; ++j) {
            float4 wl = wl4[q * 8 + j], wr = wr4[q * 8 + j];
            py.x += rr[j] * wl.x; py.y += rr[j] * wl.y;
            py.z += rr[j] * wl.z; py.w += rr[j] * wl.w;
            pz.x += rr[j] * wr.x; pz.y += rr[j] * wr.y;
            pz.z += rr[j] * wr.z; pz.w += rr[j] * wr.w;
        }
#pragma unroll
        for (int off = 1; off < 16; off <<= 1) {
            py.x += __shfl_xor(py.x, off, 16); py.y += __shfl_xor(py.y, off, 16);
            py.z += __shfl_xor(py.z, off, 16); py.w += __shfl_xor(py.w, off, 16);
            pz.x += __shfl_xor(pz.x, off, 16); pz.y += __shfl_xor(pz.y, off, 16);
            pz.z += __shfl_xor(pz.z, off, 16); pz.w += __shfl_xor(pz.w, off, 16);
        }
        if (q == 0) {
            ((float4*)y4)[n] = py;
            float4 b2 = *(const float4*)bl2;
            float4 o;
            o.x = pz.x + b2.x; o.y = pz.y + b2.y;
            o.z = pz.z + b2.z; o.w = pz.w + b2.w;
            ((float4*)outz)[n] = o;
        }
    }
}

// ================= K7: final 4-wide aggregation + duplicate write ===========
__global__ void k_agg4(const float* __restrict__ y4,
                       const int* __restrict__ offs,
                       const int* __restrict__ csr,
                       const float* __restrict__ invd,
                       float* __restrict__ out) {
    int tid = blockIdx.x * blockDim.x + threadIdx.x;
    int n = tid >> 2, c = tid & 3;
    if (n >= NNODES) return;
    int beg = offs[n], end = offs[n + 1];
    float acc = 0;
    int i = beg;
    for (; i + 4 <= end; i += 4) {
        int s0 = csr[i], s1 = csr[i + 1], s2 = csr[i + 2], s3 = csr[i + 3];
        float v0 = y4[(size_t)s0 * 4 + c];
        float v1 = y4[(size_t)s1 * 4 + c];
        float v2 = y4[(size_t)s2 * 4 + c];
        float v3 = y4[(size_t)s3 * 4 + c];
        acc += v0; acc += v1; acc += v2; acc += v3;
    }
    for (; i < end; ++i) acc += y4[(size_t)csr[i] * 4 + c];
    float r = fmaf(acc, invd[n], out[(size_t)n * 4 + c]);
    out[(size_t)n * 4 + c] = r;
    out[(size_t)NNODES * NCLS + (size_t)n * 4 + c] = r;
}

extern "C" void kernel_launch(void* const* d_in, const int* in_sizes, int n_in,
                              void* d_out, int out_size, void* d_ws, size_t ws_size,
                              hipStream_t stream) {
    const float* x   = (const float*)d_in[0];
    const int* ei    = (const int*)d_in[1];
    const float* Wl0 = (const float*)d_in[2];
    const float* bl0 = (const float*)d_in[3];
    const float* Wr0 = (const float*)d_in[4];
    const float* Wl1 = (const float*)d_in[5];
    const float* bl1 = (const float*)d_in[6];
    const float* Wr1 = (const float*)d_in[7];
    const float* Wl2 = (const float*)d_in[8];
    const float* bl2 = (const float*)d_in[9];
    const float* Wr2 = (const float*)d_in[10];

    const int* src = ei;
    const int* dst = ei + NEDGES;

    float* out = (float*)d_out;
    float* h2  = out + 2 * (size_t)NNODES * NCLS;

    char* ws = (char*)d_ws;
    int*   offs = (int*)(ws + 0);              // 50001 ints
    float* invd = (float*)(ws + 200192);       // N floats
    int*   bcnt = (int*)(ws + 400384);         // NB ints
    int*   bcur = (int*)(ws + 401408);         // NB ints (memset with bcnt)
    int*   csr  = (int*)(ws + 402432);         // E ints
    u8*    y0   = (u8*)(ws + 3602432);         // N*128 fp8: layer-0 msgs (K2->K45)
    u8*    y1   = (u8*)(ws + 16402432);        // N*128 fp8: layer-1 msgs (K45->K6)
    u32*   ebuf = (u32*)(ws + 22802432);       // E u32: K2->K3 (dead before y1? no:
                                               // separate region, no alias needed)
    u16*   zb   = (u16*)(ws + 29202432);       // N*128 bf16 self-term (both layers)
    float* y4   = (float*)(ws + 42002432);     // N*4 floats
    u16*   Bp0  = (u16*)(ws + 42802432);       // 32768 bf16
    u16*   Bp1  = (u16*)(ws + 42867968);       // 32768 bf16

    hipMemsetAsync(bcnt, 0, 2048, stream);     // bcnt + bcur

    // K1: bucket histogram + pack both layers' weights
    k_pre<<<1038, 256, 0, stream>>>(dst, Wl0, Wr0, Wl1, Wr1, bcnt, Bp0, Bp1);

    // K2: layer-0 MFMA (y0 fp8, zb bf16) + edge bucket scatter
    k_scatmfma<<<1564, 256, 0, stream>>>(x, (const uint4*)Bp0, bl0, y0, zb,
                                         src, dst, bcnt, bcur, ebuf);

    // K3: per-bucket CSR finalize (phase-sorted)
    k_bfinal<<<NB, 256, 0, stream>>>(ebuf, bcnt, offs, invd, csr);

    // K45: fused layer-0 aggregation + layer-1 MFMA
    k_aggmfma<<<(NNODES + 63) / 64, 256, 0, stream>>>(
        y0, offs, csr, invd, (const uint4*)Bp1, bl1, y1, zb);

    // K6: layer-1 aggregation (fp32 h2 out) + fused final-layer transform
    k_agg<0, 0, 1><<<NNODES / 16, 256, 0, stream>>>(
        y1, offs, csr, invd, zb, nullptr, h2,
        Wl2, Wr2, bl2, y4, out);

    // K7: final aggregation, duplicate write
    k_agg4<<<(NNODES * NCLS + 255) / 256, 256, 0, stream>>>(y4, offs, csr, invd, out);
}

// Round 12
// 231.439 us; speedup vs baseline: 1.0736x; 1.0736x over previous
//
#include <hip/hip_runtime.h>
#include <hip/hip_bf16.h>
#include <stdint.h>

#define NNODES 50000
#define NEDGES 800000
#define FDIM   128
#define NCLS   4
#define NB     196        // buckets of 256 nodes
#define ECAP   6144       // LDS edge-stage capacity per bucket (mean 4082)
#define LPITCH 136        // LDS row pitch in u16 (272B)
#define NPH    8          // source phases (src>>13) for gather L2 locality
#define SCAP   768        // LDS csr-slice capacity in k_agg (mean 256)

typedef uint32_t u32;
typedef unsigned char u8;
typedef unsigned short u16;
typedef __bf16 bf16x8 __attribute__((ext_vector_type(8)));
typedef float f32x4 __attribute__((ext_vector_type(4)));
typedef float f32x2 __attribute__((ext_vector_type(2)));

__device__ __forceinline__ u16 f2bf(float f) {
    u32 u = __float_as_uint(f);
    u32 r = u + 0x7fffu + ((u >> 16) & 1u);
    return (u16)(r >> 16);
}
__device__ __forceinline__ u32 pack2(float a, float b) {
    return (u32)f2bf(a) | ((u32)f2bf(b) << 16);
}
__device__ __forceinline__ float bflo(u32 p) { return __uint_as_float(p << 16); }
__device__ __forceinline__ float bfhi(u32 p) { return __uint_as_float(p & 0xffff0000u); }

// 8 bf16 (as uint4 halves) -> 8 fp8 e4m3 packed in uint2 (hardware RNE)
__device__ __forceinline__ uint2 bf8x8_from_bf16(uint4 v) {
    uint2 o;
    o.x = __builtin_amdgcn_cvt_pk_fp8_f32(bflo(v.x), bfhi(v.x), 0,   false);
    o.x = __builtin_amdgcn_cvt_pk_fp8_f32(bflo(v.y), bfhi(v.y), o.x, true);
    o.y = __builtin_amdgcn_cvt_pk_fp8_f32(bflo(v.z), bfhi(v.z), 0,   false);
    o.y = __builtin_amdgcn_cvt_pk_fp8_f32(bflo(v.w), bfhi(v.w), o.y, true);
    return o;
}
// accumulate 8 fp8 lanes into a0..a7
__device__ __forceinline__ void acc8(uint2 v, float& a0, float& a1, float& a2,
                                     float& a3, float& a4, float& a5, float& a6,
                                     float& a7) {
    f32x2 p0 = __builtin_amdgcn_cvt_pk_f32_fp8(v.x, false);
    f32x2 p1 = __builtin_amdgcn_cvt_pk_f32_fp8(v.x, true);
    f32x2 p2 = __builtin_amdgcn_cvt_pk_f32_fp8(v.y, false);
    f32x2 p3 = __builtin_amdgcn_cvt_pk_f32_fp8(v.y, true);
    a0 += p0.x; a1 += p0.y; a2 += p1.x; a3 += p1.y;
    a4 += p2.x; a5 += p2.y; a6 += p3.x; a7 += p3.y;
}

// ================= K1: bucket histogram + both weight packs =================
__global__ void __launch_bounds__(256) k_pre(
        const int* __restrict__ dst,
        const float* __restrict__ Wl0, const float* __restrict__ Wr0,
        const float* __restrict__ Wl1, const float* __restrict__ Wr1,
        int* __restrict__ bcnt, u16* __restrict__ Bp0, u16* __restrict__ Bp1) {
    int t = threadIdx.x;
    int bid = blockIdx.x;
    if (bid < 782) {                 // ---- bhist ----
        __shared__ int h[NB];
        if (t < NB) h[t] = 0;
        __syncthreads();
        int base = bid * 1024;
#pragma unroll
        for (int i = 0; i < 4; ++i) {
            int e = base + i * 256 + t;
            if (e < NEDGES) atomicAdd(&h[dst[e] >> 8], 1);
        }
        __syncthreads();
        if (t < NB) {
            int v = h[t];
            if (v) atomicAdd(&bcnt[t], v);
        }
    } else {                          // ---- weight pack (128 blocks per layer) ----
        int layer = (bid < 910) ? 0 : 1;
        int pid = bid - (layer ? 910 : 782);
        int tid = pid * 256 + t;      // 0..32767
        int j    = tid & 7;
        int lane = (tid >> 3) & 63;
        int ks   = (tid >> 9) & 3;
        int nt   = tid >> 11;
        int col  = nt * 16 + (lane & 15);
        int k    = ks * 32 + (lane >> 4) * 8 + j;
        const float* Wl = layer ? Wl1 : Wl0;
        const float* Wr = layer ? Wr1 : Wr0;
        float v = (col < FDIM) ? Wl[k * FDIM + col] : Wr[k * FDIM + (col - FDIM)];
        (layer ? Bp1 : Bp0)[tid] = f2bf(v);
    }
}

// ============ K2: layer-0 MFMA (blocks 0..781) + edge scatter (782..1563) ===
// y written as fp8 e4m3 (128 B/row); zb stays bf16.
// ebuf aliases hb (first written in K4) — must NOT alias y/zb.
__global__ void __launch_bounds__(256) k_scatmfma(
        const float* __restrict__ x, const uint4* __restrict__ Bp,
        const float* __restrict__ bias, u8* __restrict__ y, u16* __restrict__ zb,
        const int* __restrict__ src, const int* __restrict__ dst,
        const int* __restrict__ bcnt, int* __restrict__ bcur,
        u32* __restrict__ ebuf) {
    __shared__ u16 sA[64 * LPITCH];   // 17408 B; scatter half aliases ints onto it
    int t = threadIdx.x;
    if (blockIdx.x < 782) {
        int blk = blockIdx.x;
        int wave = t >> 6, lane = t & 63, m = lane & 15, quad = lane >> 4;
        {
            int row = t >> 2, q = t & 3;
            int r = blk * 64 + row;
            if (r >= NNODES) r = NNODES - 1;
            const float4* gs = (const float4*)(x + (size_t)r * FDIM) + q * 8;
            uint4* ld = (uint4*)(sA + row * LPITCH + q * 32);
#pragma unroll
            for (int i = 0; i < 4; ++i) {
                float4 a = gs[2 * i], b = gs[2 * i + 1];
                uint4 v;
                v.x = pack2(a.x, a.y); v.y = pack2(a.z, a.w);
                v.z = pack2(b.x, b.y); v.w = pack2(b.z, b.w);
                ld[i] = v;
            }
        }
        uint4 breg[4][4];
#pragma unroll
        for (int ks = 0; ks < 4; ++ks)
#pragma unroll
            for (int nt = 0; nt < 4; ++nt)
                breg[ks][nt] = Bp[((wave * 4 + nt) * 4 + ks) * 64 + lane];
        __syncthreads();
        bf16x8 a[4][4];
#pragma unroll
        for (int mt = 0; mt < 4; ++mt)
#pragma unroll
            for (int ks = 0; ks < 4; ++ks)
                a[mt][ks] = __builtin_bit_cast(bf16x8,
                    *(const uint4*)(sA + (mt * 16 + m) * LPITCH + ks * 32 + quad * 8));
        f32x4 acc[4][4];
#pragma unroll
        for (int mt = 0; mt < 4; ++mt)
#pragma unroll
            for (int nt = 0; nt < 4; ++nt) acc[mt][nt] = (f32x4){0.f, 0.f, 0.f, 0.f};
#pragma unroll
        for (int ks = 0; ks < 4; ++ks)
#pragma unroll
            for (int nt = 0; nt < 4; ++nt) {
                bf16x8 b = __builtin_bit_cast(bf16x8, breg[ks][nt]);
#pragma unroll
                for (int mt = 0; mt < 4; ++mt)
                    acc[mt][nt] = __builtin_amdgcn_mfma_f32_16x16x32_bf16(
                        a[mt][ks], b, acc[mt][nt], 0, 0, 0);
            }
        __syncthreads();
        if (wave < 2) {
#pragma unroll
            for (int nt = 0; nt < 4; ++nt) {
                int col = (wave * 4 + nt) * 16 + m;
#pragma unroll
                for (int mt = 0; mt < 4; ++mt)
#pragma unroll
                    for (int r = 0; r < 4; ++r)
                        sA[(mt * 16 + quad * 4 + r) * LPITCH + col] = f2bf(acc[mt][nt][r]);
            }
        }
        __syncthreads();
#pragma unroll
        for (int i = 0; i < 4; ++i) {
            int g = i * 256 + t, row = g >> 4, ch = g & 15;
            int gr = blk * 64 + row;
            if (gr < NNODES) {
                uint4 v = *(const uint4*)(sA + row * LPITCH + ch * 8);
                *((uint2*)(y + (size_t)gr * FDIM) + ch) = bf8x8_from_bf16(v);
            }
        }
        __syncthreads();
        if (wave >= 2) {
#pragma unroll
            for (int nt = 0; nt < 4; ++nt) {
                int col = (wave * 4 + nt) * 16 + m - 128;
                float bv = bias[col];
#pragma unroll
                for (int mt = 0; mt < 4; ++mt)
#pragma unroll
                    for (int r = 0; r < 4; ++r)
                        sA[(mt * 16 + quad * 4 + r) * LPITCH + col] = f2bf(acc[mt][nt][r] + bv);
            }
        }
        __syncthreads();
#pragma unroll
        for (int i = 0; i < 4; ++i) {
            int g = i * 256 + t, row = g >> 4, ch = g & 15;
            int gr = blk * 64 + row;
            if (gr < NNODES)
                *((uint4*)(zb + (size_t)gr * FDIM) + ch) =
                    *(const uint4*)(sA + row * LPITCH + ch * 8);
        }
    } else {
        // ---------------- edge bucket scatter (with in-LDS bucket scan) -------
        int* hh = (int*)sA;
        int* bb = hh + 256;
        int* ss = bb + 256;
        int v = (t < NB) ? bcnt[t] : 0;
        ss[t] = v;
        __syncthreads();
        for (int off = 1; off < 256; off <<= 1) {
            int u = (t >= off) ? ss[t - off] : 0;
            __syncthreads();
            ss[t] += u;
            __syncthreads();
        }
        int boff = ss[t] - v;
        hh[t] = 0;
        __syncthreads();
        int eb = (blockIdx.x - 782) * 1024;
        int mb[4];
        u32 pk[4];
#pragma unroll
        for (int i = 0; i < 4; ++i) {
            int e = eb + i * 256 + t;
            if (e < NEDGES) {
                int d = dst[e];
                mb[i] = d >> 8;
                pk[i] = (u32)src[e] | ((u32)d << 16);
                atomicAdd(&hh[mb[i]], 1);
            } else mb[i] = -1;
        }
        __syncthreads();
        if (t < NB) {
            int c = hh[t];
            bb[t] = c ? (boff + atomicAdd(&bcur[t], c)) : 0;
            hh[t] = 0;
        }
        __syncthreads();
#pragma unroll
        for (int i = 0; i < 4; ++i) {
            if (mb[i] >= 0) {
                int r = atomicAdd(&hh[mb[i]], 1);
                ebuf[bb[mb[i]] + r] = pk[i];
            }
        }
    }
}

// ======= K3: per-bucket CSR finalize, phase-sorted (self-scans bcnt) ========
__global__ void __launch_bounds__(256) k_bfinal(
        const u32* __restrict__ ebuf, const int* __restrict__ bcnt,
        int* __restrict__ offs, float* __restrict__ invd, int* __restrict__ csr) {
    __shared__ u32 se[ECAP];
    __shared__ int deg8[256 * NPH];
    __shared__ int s[256];
    int b = blockIdx.x, t = threadIdx.x;
    int nbase = b << 8;
    int v = (t < NB) ? bcnt[t] : 0;
    s[t] = v;
    __syncthreads();
    for (int off = 1; off < 256; off <<= 1) {
        int u = (t >= off) ? s[t - off] : 0;
        __syncthreads();
        s[t] += u;
        __syncthreads();
    }
    int ebeg = s[b] - bcnt[b];
    int ecnt = bcnt[b];
    __syncthreads();
#pragma unroll
    for (int j = 0; j < NPH; ++j) deg8[t * NPH + j] = 0;
    __syncthreads();
    for (int i = t; i < ecnt; i += 256) {
        u32 e = ebuf[ebeg + i];
        if (i < ECAP) se[i] = e;
        atomicAdd(&deg8[((int)(e >> 16) - nbase) * NPH + (((int)(e & 0xffffu)) >> 13)], 1);
    }
    __syncthreads();
    int pre[NPH];
    int run = 0;
#pragma unroll
    for (int j = 0; j < NPH; ++j) { pre[j] = run; run += deg8[t * NPH + j]; }
    int d = run;
    s[t] = d;
    __syncthreads();
    for (int off = 1; off < 256; off <<= 1) {
        int u = (t >= off) ? s[t - off] : 0;
        __syncthreads();
        s[t] += u;
        __syncthreads();
    }
    int ex = s[t] - d;
    int node = nbase + t;
    if (node < NNODES) {
        offs[node] = ebeg + ex;
        invd[node] = (d > 0) ? (1.0f / (float)d) : 0.0f;
    }
    __syncthreads();
#pragma unroll
    for (int j = 0; j < NPH; ++j) deg8[t * NPH + j] = ex + pre[j];
    __syncthreads();
    for (int i = t; i < ecnt; i += 256) {
        u32 e = (i < ECAP) ? se[i] : ebuf[ebeg + i];
        int dl = (int)(e >> 16) - nbase;
        int sv = (int)(e & 0xffffu);
        int r = atomicAdd(&deg8[dl * NPH + (sv >> 13)], 1);
        csr[ebeg + r] = sv;
    }
    if (b == 0 && t == 0) offs[NNODES] = NEDGES;
}

// ===== K4/K6: gather aggregation (unroll 8) + optional fused final layer ====
template <int RELU, int OUTBF, int FUSE4>
__global__ void __launch_bounds__(256) k_agg(
        const u8* __restrict__ y, const int* __restrict__ offs,
        const int* __restrict__ csr, const float* __restrict__ invd,
        const u16* __restrict__ zb, u16* __restrict__ outb, float* __restrict__ outf,
        const float* __restrict__ Wl2, const float* __restrict__ Wr2,
        const float* __restrict__ bl2, float* __restrict__ y4,
        float* __restrict__ outz) {
    __shared__ int sidx[SCAP];
    int t = threadIdx.x;
    int n0 = blockIdx.x * 16;
    int base0 = offs[n0];
    int ecnt = offs[n0 + 16] - base0;
    for (int i = t; i < ecnt && i < SCAP; i += 256) sidx[i] = csr[base0 + i];
    __syncthreads();
    int nl = t >> 4, q = t & 15;
    int n = n0 + nl;
    int beg = offs[n], end = offs[n + 1];
    float a0 = 0, a1 = 0, a2 = 0, a3 = 0, a4 = 0, a5 = 0, a6 = 0, a7 = 0;
    const u8* yq = y + q * 8;
    int ii = beg;
    for (; ii + 8 <= end; ii += 8) {
        int li = ii - base0;
        int s[8];
        if (li + 7 < SCAP) {
#pragma unroll
            for (int k = 0; k < 8; ++k) s[k] = sidx[li + k];
        } else {
#pragma unroll
            for (int k = 0; k < 8; ++k) s[k] = csr[ii + k];
        }
        uint2 v[8];
#pragma unroll
        for (int k = 0; k < 8; ++k)
            v[k] = *(const uint2*)(yq + (size_t)s[k] * FDIM);
#pragma unroll
        for (int k = 0; k < 8; ++k)
            acc8(v[k], a0, a1, a2, a3, a4, a5, a6, a7);
    }
    for (; ii < end; ++ii) {
        int li = ii - base0;
        int s = (li < SCAP) ? sidx[li] : csr[ii];
        uint2 v = *(const uint2*)(yq + (size_t)s * FDIM);
        acc8(v, a0, a1, a2, a3, a4, a5, a6, a7);
    }
    float iv = invd[n];
    uint4 zv = *(const uint4*)(zb + (size_t)n * FDIM + q * 8);
    float r0 = fmaf(a0, iv, bflo(zv.x)), r1 = fmaf(a1, iv, bfhi(zv.x));
    float r2 = fmaf(a2, iv, bflo(zv.y)), r3 = fmaf(a3, iv, bfhi(zv.y));
    float r4 = fmaf(a4, iv, bflo(zv.z)), r5 = fmaf(a5, iv, bfhi(zv.z));
    float r6 = fmaf(a6, iv, bflo(zv.w)), r7 = fmaf(a7, iv, bfhi(zv.w));
    if (RELU) {
        r0 = fmaxf(r0, 0.f); r1 = fmaxf(r1, 0.f); r2 = fmaxf(r2, 0.f); r3 = fmaxf(r3, 0.f);
        r4 = fmaxf(r4, 0.f); r5 = fmaxf(r5, 0.f); r6 = fmaxf(r6, 0.f); r7 = fmaxf(r7, 0.f);
    }
    if (OUTBF) {
        uint4 o;
        o.x = pack2(r0, r1); o.y = pack2(r2, r3);
        o.z = pack2(r4, r5); o.w = pack2(r6, r7);
        *(uint4*)(outb + (size_t)n * FDIM + q * 8) = o;
    } else {
        float* o = outf + (size_t)n * FDIM + q * 8;
        ((float4*)o)[0] = make_float4(r0, r1, r2, r3);
        ((float4*)o)[1] = make_float4(r4, r5, r6, r7);
    }
    if (FUSE4) {
        float rr[8] = {r0, r1, r2, r3, r4, r5, r6, r7};
        float4 py = {0, 0, 0, 0}, pz = {0, 0, 0, 0};
        const float4* wl4 = (const float4*)Wl2;
        const float4* wr4 = (const float4*)Wr2;
#pragma unroll
        for (int j = 0; j < 8; ++j) {
            float4 wl = wl4[q * 8 + j], wr = wr4[q * 8 + j];
            py.x += rr[j] * wl.x; py.y += rr[j] * wl.y;
            py.z += rr[j] * wl.z; py.w += rr[j] * wl.w;
            pz.x += rr[j] * wr.x; pz.y += rr[j] * wr.y;
            pz.z += rr[j] * wr.z; pz.w += rr[j] * wr.w;
        }
#pragma unroll
        for (int off = 1; off < 16; off <<= 1) {
            py.x += __shfl_xor(py.x, off, 16); py.y += __shfl_xor(py.y, off, 16);
            py.z += __shfl_xor(py.z, off, 16); py.w += __shfl_xor(py.w, off, 16);
            pz.x += __shfl_xor(pz.x, off, 16); pz.y += __shfl_xor(pz.y, off, 16);
            pz.z += __shfl_xor(pz.z, off, 16); pz.w += __shfl_xor(pz.w, off, 16);
        }
        if (q == 0) {
            ((float4*)y4)[n] = py;
            float4 b2 = *(const float4*)bl2;
            float4 o;
            o.x = pz.x + b2.x; o.y = pz.y + b2.y;
            o.z = pz.z + b2.z; o.w = pz.w + b2.w;
            ((float4*)outz)[n] = o;
        }
    }
}

// ================= K5: layer-1 MFMA (bf16 input, fp8 y out) =================
__global__ void __launch_bounds__(256) k_mfma1(
        const u16* __restrict__ in, const uint4* __restrict__ Bp,
        const float* __restrict__ bias, u8* __restrict__ y, u16* __restrict__ zb) {
    __shared__ u16 sA[64 * LPITCH];
    int t = threadIdx.x;
    int blk = blockIdx.x;
    int wave = t >> 6, lane = t & 63, m = lane & 15, quad = lane >> 4;
    {
        int row = t >> 2, q = t & 3;
        int r = blk * 64 + row;
        if (r >= NNODES) r = NNODES - 1;
        const uint4* gsrc = (const uint4*)(in + (size_t)r * FDIM);
        uint4* ldst = (uint4*)(sA + row * LPITCH);
#pragma unroll
        for (int i = 0; i < 4; ++i) ldst[q * 4 + i] = gsrc[q * 4 + i];
    }
    uint4 breg[4][4];
#pragma unroll
    for (int ks = 0; ks < 4; ++ks)
#pragma unroll
        for (int nt = 0; nt < 4; ++nt)
            breg[ks][nt] = Bp[((wave * 4 + nt) * 4 + ks) * 64 + lane];
    __syncthreads();
    bf16x8 a[4][4];
#pragma unroll
    for (int mt = 0; mt < 4; ++mt)
#pragma unroll
        for (int ks = 0; ks < 4; ++ks)
            a[mt][ks] = __builtin_bit_cast(bf16x8,
                *(const uint4*)(sA + (mt * 16 + m) * LPITCH + ks * 32 + quad * 8));
    f32x4 acc[4][4];
#pragma unroll
    for (int mt = 0; mt < 4; ++mt)
#pragma unroll
        for (int nt = 0; nt < 4; ++nt) acc[mt][nt] = (f32x4){0.f, 0.f, 0.f, 0.f};
#pragma unroll
    for (int ks = 0; ks < 4; ++ks)
#pragma unroll
        for (int nt = 0; nt < 4; ++nt) {
            bf16x8 b = __builtin_bit_cast(bf16x8, breg[ks][nt]);
#pragma unroll
            for (int mt = 0; mt < 4; ++mt)
                acc[mt][nt] = __builtin_amdgcn_mfma_f32_16x16x32_bf16(
                    a[mt][ks], b, acc[mt][nt], 0, 0, 0);
        }
    __syncthreads();
    if (wave < 2) {
#pragma unroll
        for (int nt = 0; nt < 4; ++nt) {
            int col = (wave * 4 + nt) * 16 + m;
#pragma unroll
            for (int mt = 0; mt < 4; ++mt)
#pragma unroll
                for (int r = 0; r < 4; ++r)
                    sA[(mt * 16 + quad * 4 + r) * LPITCH + col] = f2bf(acc[mt][nt][r]);
        }
    }
    __syncthreads();
#pragma unroll
    for (int i = 0; i < 4; ++i) {
        int g = i * 256 + t, row = g >> 4, ch = g & 15;
        int gr = blk * 64 + row;
        if (gr < NNODES) {
            uint4 v = *(const uint4*)(sA + row * LPITCH + ch * 8);
            *((uint2*)(y + (size_t)gr * FDIM) + ch) = bf8x8_from_bf16(v);
        }
    }
    __syncthreads();
    if (wave >= 2) {
#pragma unroll
        for (int nt = 0; nt < 4; ++nt) {
            int col = (wave * 4 + nt) * 16 + m - 128;
            float bv = bias[col];
#pragma unroll
            for (int mt = 0; mt < 4; ++mt)
#pragma unroll
                for (int r = 0; r < 4; ++r)
                    sA[(mt * 16 + quad * 4 + r) * LPITCH + col] = f2bf(acc[mt][nt][r] + bv);
        }
    }
    __syncthreads();
#pragma unroll
    for (int i = 0; i < 4; ++i) {
        int g = i * 256 + t, row = g >> 4, ch = g & 15;
        int gr = blk * 64 + row;
        if (gr < NNODES)
            *((uint4*)(zb + (size_t)gr * FDIM) + ch) =
                *(const uint4*)(sA + row * LPITCH + ch * 8);
    }
}

// ================= K7: final 4-wide aggregation + duplicate write ===========
__global__ void k_agg4(const float* __restrict__ y4,
                       const int* __restrict__ offs,
                       const int* __restrict__ csr,
                       const float* __restrict__ invd,
                       float* __restrict__ out) {
    int tid = blockIdx.x * blockDim.x + threadIdx.x;
    int n = tid >> 2, c = tid & 3;
    if (n >= NNODES) return;
    int beg = offs[n], end = offs[n + 1];
    float acc = 0;
    int i = beg;
    for (; i + 4 <= end; i += 4) {
        int s0 = csr[i], s1 = csr[i + 1], s2 = csr[i + 2], s3 = csr[i + 3];
        float v0 = y4[(size_t)s0 * 4 + c];
        float v1 = y4[(size_t)s1 * 4 + c];
        float v2 = y4[(size_t)s2 * 4 + c];
        float v3 = y4[(size_t)s3 * 4 + c];
        acc += v0; acc += v1; acc += v2; acc += v3;
    }
    for (; i < end; ++i) acc += y4[(size_t)csr[i] * 4 + c];
    float r = fmaf(acc, invd[n], out[(size_t)n * 4 + c]);
    out[(size_t)n * 4 + c] = r;
    out[(size_t)NNODES * NCLS + (size_t)n * 4 + c] = r;
}

extern "C" void kernel_launch(void* const* d_in, const int* in_sizes, int n_in,
                              void* d_out, int out_size, void* d_ws, size_t ws_size,
                              hipStream_t stream) {
    const float* x   = (const float*)d_in[0];
    const int* ei    = (const int*)d_in[1];
    const float* Wl0 = (const float*)d_in[2];
    const float* bl0 = (const float*)d_in[3];
    const float* Wr0 = (const float*)d_in[4];
    const float* Wl1 = (const float*)d_in[5];
    const float* bl1 = (const float*)d_in[6];
    const float* Wr1 = (const float*)d_in[7];
    const float* Wl2 = (const float*)d_in[8];
    const float* bl2 = (const float*)d_in[9];
    const float* Wr2 = (const float*)d_in[10];

    const int* src = ei;
    const int* dst = ei + NEDGES;

    float* out = (float*)d_out;
    float* h2  = out + 2 * (size_t)NNODES * NCLS;

    char* ws = (char*)d_ws;
    int*   offs = (int*)(ws + 0);              // 50001 ints
    float* invd = (float*)(ws + 200192);       // N floats
    int*   bcnt = (int*)(ws + 400384);         // NB ints
    int*   bcur = (int*)(ws + 401408);         // NB ints (memset with bcnt)
    int*   csr  = (int*)(ws + 402432);         // E ints
    u8*    y    = (u8*)(ws + 3602432);         // N*128 fp8 e4m3 (6.4 MB)
    u16*   hb   = (u16*)(ws + 16402432);       // N*128 bf16
    u16*   zb   = (u16*)(ws + 29202432);       // N*128 bf16
    u32*   ebuf = (u32*)hb;                    // E u32 aliases hb: written K2,
                                               // consumed K3; hb first written K4
    float* y4   = (float*)(ws + 42002432);     // N*4 floats
    u16*   Bp0  = (u16*)(ws + 42802432);       // 32768 bf16
    u16*   Bp1  = (u16*)(ws + 42867968);       // 32768 bf16

    hipMemsetAsync(bcnt, 0, 2048, stream);     // bcnt + bcur

    // K1: bucket histogram + pack both layers' weights
    k_pre<<<1038, 256, 0, stream>>>(dst, Wl0, Wr0, Wl1, Wr1, bcnt, Bp0, Bp1);

    // K2: layer-0 MFMA + edge bucket scatter
    k_scatmfma<<<1564, 256, 0, stream>>>(x, (const uint4*)Bp0, bl0, y, zb,
                                         src, dst, bcnt, bcur, ebuf);

    // K3: per-bucket CSR finalize (phase-sorted)
    k_bfinal<<<NB, 256, 0, stream>>>(ebuf, bcnt, offs, invd, csr);

    // K4: layer-0 aggregation (relu, bf16 out)
    k_agg<1, 1, 0><<<NNODES / 16, 256, 0, stream>>>(
        y, offs, csr, invd, zb, hb, nullptr,
        nullptr, nullptr, nullptr, nullptr, nullptr);

    // K5: layer-1 MFMA
    k_mfma1<<<(NNODES + 63) / 64, 256, 0, stream>>>(hb, (const uint4*)Bp1, bl1, y, zb);

    // K6: layer-1 aggregation (fp32 h2 out) + fused final-layer transform
    k_agg<0, 0, 1><<<NNODES / 16, 256, 0, stream>>>(
        y, offs, csr, invd, zb, nullptr, h2,
        Wl2, Wr2, bl2, y4, out);

    // K7: final aggregation, duplicate write
    k_agg4<<<(NNODES * NCLS + 255) / 256, 256, 0, stream>>>(y4, offs, csr, invd, out);
}